// Round 9
// baseline (269.471 us; speedup 1.0000x reference)
//
#include <hip/hip_runtime.h>
#include <hip/hip_bf16.h>
#include <cstdint>

#define DEV __device__ __forceinline__

constexpr int D_   = 256;
constexpr int CF_  = 768;
constexpr int NTOK = 131072;             // 2*256*256
constexpr int SHIFT = 4;
constexpr float EPS_ = 1e-6f;

typedef short bf16x8 __attribute__((ext_vector_type(8)));
typedef float f32x4  __attribute__((ext_vector_type(4)));

DEV float bf2f(unsigned short u) {
    unsigned v = ((unsigned)u) << 16;
    return __builtin_bit_cast(float, v);
}
DEV unsigned short f2bf(float f) {
    unsigned u = __builtin_bit_cast(unsigned, f);
    unsigned r = (u + 0x7fffu + ((u >> 16) & 1u)) >> 16;
    return (unsigned short)r;
}
DEV unsigned cvtpk(float lo, float hi) {      // packed f32->bf16 RNE (no builtin on gfx950)
    unsigned r;
    asm("v_cvt_pk_bf16_f32 %0, %1, %2" : "=v"(r) : "v"(lo), "v"(hi));
    return r;
}
DEV float wave_sum(float v) {
    #pragma unroll
    for (int o = 32; o; o >>= 1) v += __shfl_xor(v, o, 64);
    return v;
}
DEV void gl_lds16(const void* g, void* l) {
    __builtin_amdgcn_global_load_lds(
        (const __attribute__((address_space(1))) void*)g,
        (__attribute__((address_space(3))) void*)l, 16, 0, 0);
}

// ---------------- kernel 1: modulation c = silu(cond) @ mod_w.T + mod_b ----------------
__global__ void k_mod(const float* __restrict__ cond, const float* __restrict__ mod_w,
                      const float* __restrict__ mod_b, float* __restrict__ c) {
    int wv = threadIdx.x >> 6, lane = threadIdx.x & 63;
    int idx = blockIdx.x * 4 + wv;
    int b = idx / (3 * D_), j = idx % (3 * D_);
    float acc = 0.f;
    for (int k = lane; k < CF_; k += 64) {
        float cv = cond[b * CF_ + k];
        float s = cv / (1.f + expf(-cv));
        acc += s * mod_w[(size_t)j * CF_ + k];
    }
    acc = wave_sum(acc);
    if (lane == 0) c[b * (3 * D_) + j] = acc + mod_b[j];
}

// ---------------- kernel 2: merged prep: xn bf16 (RMS+mod) AND weight casts ----------------
__global__ void k_prep(const float* __restrict__ x, const float* __restrict__ c,
                       const float* __restrict__ norm_scale,
                       const float* __restrict__ qkv_w, const float* __restrict__ out_w,
                       unsigned short* __restrict__ xnb,
                       unsigned short* __restrict__ qkvwb, unsigned short* __restrict__ outwb) {
    if (blockIdx.x < 32768) {
        int wv = threadIdx.x >> 6, lane = threadIdx.x & 63;
        int t = blockIdx.x * 4 + wv;
        int b = t >> 16;
        const float* xp = x + (size_t)t * D_ + lane * 4;
        float4 v = *(const float4*)xp;
        float s = v.x * v.x + v.y * v.y + v.z * v.z + v.w * v.w;
        s = wave_sum(s);
        float rinv = rsqrtf(s * (1.f / D_) + EPS_);
        float4 sc = *(const float4*)(c + b * 768 + 256 + lane * 4);
        float4 sh = *(const float4*)(c + b * 768 + lane * 4);
        float4 ns = *(const float4*)(norm_scale + lane * 4);
        float y0 = v.x * rinv * ((1.f + sc.x) * ns.x) + sh.x;
        float y1 = v.y * rinv * ((1.f + sc.y) * ns.y) + sh.y;
        float y2 = v.z * rinv * ((1.f + sc.z) * ns.z) + sh.z;
        float y3 = v.w * rinv * ((1.f + sc.w) * ns.w) + sh.w;
        uint2 p;
        p.x = cvtpk(y0, y1);
        p.y = cvtpk(y2, y3);
        *(uint2*)(xnb + (size_t)t * D_ + lane * 4) = p;
    } else {
        int i = (blockIdx.x - 32768) * 256 + threadIdx.x;
        const float* src; unsigned short* dst; int off;
        if (i < 49152) { src = qkv_w; dst = qkvwb; off = i * 4; }
        else           { src = out_w; dst = outwb; off = (i - 49152) * 4; }
        float4 v = *(const float4*)(src + off);
        uint2 p;
        p.x = cvtpk(v.x, v.y);
        p.y = cvtpk(v.z, v.w);
        *(uint2*)(dst + off) = p;
    }
}

// ---------------- kernel 3: QKV GEMM, 2-phase pipelined, swizzled LDS, wide stores ----
__global__ __launch_bounds__(256) void k_qkv_mfma(const unsigned short* __restrict__ xnb,
                                                  const unsigned short* __restrict__ wb,
                                                  const float* __restrict__ attn_scale,
                                                  unsigned short* __restrict__ qkv) {
    __shared__ unsigned short SM[17408];           // loop: As[2][4096]+Bs[2][4096]; epi: [128][136]
    unsigned short* As = SM;
    unsigned short* Bs = SM + 8192;
    const int t = threadIdx.x, l = t & 63, w = t >> 6;
    const int bid = blockIdx.x;
    const int lid = (bid & 7) * 768 + (bid >> 3);  // 6144 blocks, 8 XCD chunks of 768
    const int m0 = (lid / 6) * 128;
    const int nt = lid % 6;
    const int n0 = nt * 128;
    const int wm = w >> 1, wn = w & 1;
    f32x4 acc[4][4] = {};

    const int srow = w * 32 + (l >> 2);
    const int scol = (((l & 3) ^ ((l >> 3) & 3)) * 8);   // swizzled source slot
    const unsigned short* aA = xnb + (size_t)(m0 + srow) * 256 + scol;
    const unsigned short* aB = wb  + (size_t)(n0 + srow) * 256 + scol;

    auto stage = [&](int buf, int k0) {
        gl_lds16(aA + k0,            &As[buf * 4096 + (w * 2 + 0) * 512]);
        gl_lds16(aA + k0 + 16 * 256, &As[buf * 4096 + (w * 2 + 1) * 512]);
        gl_lds16(aB + k0,            &Bs[buf * 4096 + (w * 2 + 0) * 512]);
        gl_lds16(aB + k0 + 16 * 256, &Bs[buf * 4096 + (w * 2 + 1) * 512]);
    };

    const int q16 = l & 15, g = l >> 4;
    const int rslot = (g ^ ((q16 >> 1) & 3)) * 8;        // swizzled read slot

    stage(0, 0);
    __syncthreads();
    int cur = 0;
    #pragma unroll
    for (int step = 0; step < 8; ++step) {
        if (step < 7) stage(cur ^ 1, (step + 1) * 32);   // prefetch next tile
        bf16x8 af[4], bff[4];
        #pragma unroll
        for (int i = 0; i < 4; i++) {
            af[i]  = *(const bf16x8*)&As[cur * 4096 + (wm * 64 + i * 16 + q16) * 32 + rslot];
            bff[i] = *(const bf16x8*)&Bs[cur * 4096 + (wn * 64 + i * 16 + q16) * 32 + rslot];
        }
        #pragma unroll
        for (int i = 0; i < 4; i++)
            #pragma unroll
            for (int j = 0; j < 4; j++)
                acc[i][j] = __builtin_amdgcn_mfma_f32_16x16x32_bf16(af[i], bff[j], acc[i][j], 0, 0, 0);
        __syncthreads();
        cur ^= 1;
    }

    // ---- epilogue: transform in-register, stage to LDS [128][136], coalesced stores ----
    const int rl0 = wm * 64 + g * 4;
    const int cl0 = wn * 64 + q16;

    if (nt < 4) {
        const int head = (nt * 2 + wn) & 3;
        const float ssc = sqrtf(attn_scale[head]);
        const float freq = expf(1.14472988584940017f + (float)((q16 & 7) * 4 + head) * 0.07195578545544534f);
        #pragma unroll
        for (int i = 0; i < 4; i++) {
            #pragma unroll
            for (int rg = 0; rg < 4; rg++) {
                float ss = acc[i][0][rg] * acc[i][0][rg] + acc[i][1][rg] * acc[i][1][rg]
                         + acc[i][2][rg] * acc[i][2][rg] + acc[i][3][rg] * acc[i][3][rg];
                ss += __shfl_xor(ss, 1, 64);
                ss += __shfl_xor(ss, 2, 64);
                ss += __shfl_xor(ss, 4, 64);
                ss += __shfl_xor(ss, 8, 64);
                const float rinv = ssc * rsqrtf(ss + EPS_);
                const int rl = rl0 + i * 16 + rg;
                const int row = m0 + rl;
                const int oy = (row >> 8) & 255, ox = row & 255;
                const float ph = -1.f + (float)oy * (2.f / 255.f);
                const float pw = -1.f + (float)ox * (2.f / 255.f);
                const float th = ((q16 < 8) ? ph : pw) * freq;
                float sn, cs;
                __sincosf(th, &sn, &cs);
                const float n0v = acc[i][0][rg] * rinv;
                const float n1v = acc[i][1][rg] * rinv;
                const float n2v = acc[i][2][rg] * rinv;
                const float n3v = acc[i][3][rg] * rinv;
                SM[rl * 136 + cl0]      = f2bf(n0v * cs - n1v * sn);
                SM[rl * 136 + cl0 + 16] = f2bf(n1v * cs + n0v * sn);
                SM[rl * 136 + cl0 + 32] = f2bf(n2v);
                SM[rl * 136 + cl0 + 48] = f2bf(n3v);
            }
        }
    } else {
        #pragma unroll
        for (int i = 0; i < 4; i++)
            #pragma unroll
            for (int rg = 0; rg < 4; rg++) {
                const int rl = rl0 + i * 16 + rg;
                #pragma unroll
                for (int j = 0; j < 4; j++)
                    SM[rl * 136 + cl0 + j * 16] = f2bf(acc[i][j][rg]);
            }
    }
    __syncthreads();

    {
        const int cr = (t & 15) * 8, rr = t >> 4;
        #pragma unroll
        for (int it = 0; it < 8; it++) {
            const int rl = rr + it * 16;
            uint4 vv = *(const uint4*)&SM[rl * 136 + cr];
            *(uint4*)(qkv + (size_t)(m0 + rl) * 768 + n0 + cr) = vv;
        }
    }
}

// ---------------- kernel 4: fused window attention + out-projection + gated residual ----
// Block = 1 window, 4 waves = 4 heads. S^T = mfma(K,Q); softmax in-register; P in-register
// to PV A-fragments via cvt_pk + shfl. V^T in LDS; Mem reused as ostage [64][264] bf16 for
// the out-GEMM, then AGAIN as f32 [64][132] (two col-half passes) for coalesced x+gate*o.
__global__ __launch_bounds__(256) void k_attn_out(const unsigned short* __restrict__ qkv,
                                                  const unsigned short* __restrict__ outwb,
                                                  const float* __restrict__ x,
                                                  const float* __restrict__ c,
                                                  float* __restrict__ out) {
    __shared__ unsigned short Mem[4 * 64 * 72];    // 36.9 KB, triple-reused
    __shared__ float Ls[4][64];
    const int w = threadIdx.x >> 6, l = threadIdx.x & 63;
    const int t = threadIdx.x;
    const int bid = blockIdx.x;
    const int lid = (bid & 7) * 256 + (bid >> 3);  // XCD-contiguous windows
    const int wx = lid & 31, wy = (lid >> 5) & 31, b = lid >> 10;
    const int head = w;
    const int g = l >> 4, q16 = l & 15;
    unsigned short* Vt = &Mem[w * 4608];

    auto tokof = [&](int p) -> size_t {
        int oy = (wy * 8 + (p >> 3) - SHIFT) & 255;
        int ox = (wx * 8 + (p & 7) - SHIFT) & 255;
        return (size_t)b * 65536 + (size_t)oy * 256 + ox;
    };

    // ---- stage V^T (this wave's head): Vt[d][key] ----
    {
        const unsigned short* vp = qkv + tokof(l) * 768 + 512 + head * 64;
        uint4 vr[8];
        #pragma unroll
        for (int i = 0; i < 8; i++) vr[i] = *(const uint4*)(vp + i * 8);
        #pragma unroll
        for (int i = 0; i < 8; i++) {
            unsigned wd[4] = {vr[i].x, vr[i].y, vr[i].z, vr[i].w};
            #pragma unroll
            for (int cc = 0; cc < 4; cc++) {
                Vt[(i * 8 + cc * 2 + 0) * 72 + l] = (unsigned short)(wd[cc] & 0xffff);
                Vt[(i * 8 + cc * 2 + 1) * 72 + l] = (unsigned short)(wd[cc] >> 16);
            }
        }
    }

    // ---- K (A) and Q (B) fragments direct from global ----
    bf16x8 af[4][2], bq[4][2];
    #pragma unroll
    for (int i = 0; i < 4; i++) {
        size_t tk = tokof(i * 16 + q16);
        const unsigned short* kp = qkv + tk * 768 + 256 + head * 64 + g * 8;
        af[i][0] = *(const bf16x8*)(kp);
        af[i][1] = *(const bf16x8*)(kp + 32);
        const unsigned short* qp = qkv + tk * 768 + head * 64 + g * 8;
        bq[i][0] = *(const bf16x8*)(qp);
        bq[i][1] = *(const bf16x8*)(qp + 32);
    }

    // ---- S^T = K @ Q^T ----
    f32x4 st[4][4] = {};
    #pragma unroll
    for (int ks = 0; ks < 2; ks++)
        #pragma unroll
        for (int i = 0; i < 4; i++)
            #pragma unroll
            for (int j = 0; j < 4; j++)
                st[i][j] = __builtin_amdgcn_mfma_f32_16x16x32_bf16(af[i][ks], bq[j][ks], st[i][j], 0, 0, 0);

    // ---- boundary-window mask ----
    const bool topw = (wy == 0), leftw = (wx == 0);
    if (topw || leftw) {
        #pragma unroll
        for (int j = 0; j < 4; j++) {
            int query = 16 * j + q16;
            bool qa = ((query >> 3) < 4), qlf = ((query & 7) < 4);
            #pragma unroll
            for (int i = 0; i < 4; i++)
                #pragma unroll
                for (int r = 0; r < 4; r++) {
                    int key = 16 * i + 4 * g + r;
                    bool ok = (!leftw || (qlf == ((key & 7) < 4))) &&
                              (!topw || (qa == ((key >> 3) < 4)));
                    if (!ok) st[i][j][r] = -1e9f;
                }
        }
    }

    // ---- softmax over keys ----
    #pragma unroll
    for (int j = 0; j < 4; j++) {
        float m = -1e30f;
        #pragma unroll
        for (int i = 0; i < 4; i++)
            #pragma unroll
            for (int r = 0; r < 4; r++) m = fmaxf(m, st[i][j][r]);
        m = fmaxf(m, __shfl_xor(m, 16, 64));
        m = fmaxf(m, __shfl_xor(m, 32, 64));
        float s = 0.f;
        #pragma unroll
        for (int i = 0; i < 4; i++)
            #pragma unroll
            for (int r = 0; r < 4; r++) {
                float p = __expf(st[i][j][r] - m);
                st[i][j][r] = p;
                s += p;
            }
        s += __shfl_xor(s, 16, 64);
        s += __shfl_xor(s, 32, 64);
        if (g == 0) Ls[w][16 * j + q16] = s;
    }
    __syncthreads();    // Vt fully staged

    // ---- PV with in-register P transpose ----
    bf16x8 vb[4][2];
    #pragma unroll
    for (int j = 0; j < 4; j++) {
        vb[j][0] = *(const bf16x8*)&Vt[(16 * j + q16) * 72 + g * 8];
        vb[j][1] = *(const bf16x8*)&Vt[(16 * j + q16) * 72 + 32 + g * 8];
    }
    const int ghi = g >> 1;
    const int srcl0 = ((2 * (g & 1)) & 3) * 16 + q16;
    const int srcl1 = ((2 * (g & 1) + 1) & 3) * 16 + q16;
    f32x4 o[4][4] = {};
    #pragma unroll
    for (int qb = 0; qb < 4; qb++) {
        unsigned pk[8];
        #pragma unroll
        for (int ih = 0; ih < 4; ih++) {
            pk[2 * ih]     = cvtpk(st[ih][qb][0], st[ih][qb][1]);
            pk[2 * ih + 1] = cvtpk(st[ih][qb][2], st[ih][qb][3]);
        }
        unsigned pw[8];
        #pragma unroll
        for (int ks = 0; ks < 2; ks++) {
            #pragma unroll
            for (int wd = 0; wd < 4; wd++) {
                const int srcl = (wd < 2) ? srcl0 : srcl1;
                unsigned va  = (unsigned)__shfl((int)pk[4 * ks + (wd & 1)], srcl, 64);
                unsigned vbb = (unsigned)__shfl((int)pk[4 * ks + 2 + (wd & 1)], srcl, 64);
                pw[ks * 4 + wd] = ghi ? vbb : va;
            }
        }
        uint4 paw0 = {pw[0], pw[1], pw[2], pw[3]};
        uint4 paw1 = {pw[4], pw[5], pw[6], pw[7]};
        bf16x8 paA = __builtin_bit_cast(bf16x8, paw0);
        bf16x8 paB = __builtin_bit_cast(bf16x8, paw1);
        #pragma unroll
        for (int j = 0; j < 4; j++) {
            o[qb][j] = __builtin_amdgcn_mfma_f32_16x16x32_bf16(paA, vb[j][0], o[qb][j], 0, 0, 0);
            o[qb][j] = __builtin_amdgcn_mfma_f32_16x16x32_bf16(paB, vb[j][1], o[qb][j], 0, 0, 0);
        }
    }

    // ---- scale by 1/l, stage O bf16 into LDS [64][264] ----
    __syncthreads();
    unsigned short* ost = Mem;
    #pragma unroll
    for (int i = 0; i < 4; i++) {
        float4 lv = *(const float4*)&Ls[w][16 * i + 4 * g];
        float lvr[4] = {lv.x, lv.y, lv.z, lv.w};
        #pragma unroll
        for (int r = 0; r < 4; r++) {
            const float invl = 1.f / lvr[r];
            const int row = 16 * i + 4 * g + r;
            #pragma unroll
            for (int j = 0; j < 4; j++)
                ost[row * 264 + head * 64 + 16 * j + q16] = f2bf(o[i][j][r] * invl);
        }
    }
    __syncthreads();

    // ---- out projection: wave w computes cols [64w, 64w+64) ----
    f32x4 acc2[4][4] = {};
    #pragma unroll
    for (int ks = 0; ks < 8; ks++) {
        bf16x8 a2[4], b2[4];
        #pragma unroll
        for (int i = 0; i < 4; i++)
            a2[i] = *(const bf16x8*)&ost[(16 * i + q16) * 264 + ks * 32 + g * 8];
        #pragma unroll
        for (int j = 0; j < 4; j++)
            b2[j] = *(const bf16x8*)&outwb[(size_t)(w * 64 + 16 * j + q16) * 256 + ks * 32 + g * 8];
        #pragma unroll
        for (int i = 0; i < 4; i++)
            #pragma unroll
            for (int j = 0; j < 4; j++)
                acc2[i][j] = __builtin_amdgcn_mfma_f32_16x16x32_bf16(a2[i], b2[j], acc2[i][j], 0, 0, 0);
    }

    // ---- coalesced epilogue: stage gate*acc2 (f32) in two col-half passes, out = x + buf ----
    float gates[4];
    #pragma unroll
    for (int j = 0; j < 4; j++) gates[j] = c[b * 768 + 512 + w * 64 + 16 * j + q16];
    float* fbuf = (float*)Mem;               // [64][132] f32 = 33.8 KB
    const int rr = t >> 2, c0 = (t & 3) * 32;
    const size_t tokr = tokof(rr);
    #pragma unroll
    for (int h = 0; h < 2; h++) {
        __syncthreads();                     // prior Mem readers done
        if ((w >> 1) == h) {
            const int cb = (w & 1) * 64;
            #pragma unroll
            for (int i = 0; i < 4; i++)
                #pragma unroll
                for (int r = 0; r < 4; r++) {
                    const int row = 16 * i + 4 * g + r;
                    #pragma unroll
                    for (int j = 0; j < 4; j++)
                        fbuf[row * 132 + cb + 16 * j + q16] = gates[j] * acc2[i][j][r];
                }
        }
        __syncthreads();
        const float* xp = x + tokr * 256 + h * 128 + c0;
        float* op = out + tokr * 256 + h * 128 + c0;
        #pragma unroll
        for (int k4 = 0; k4 < 8; k4++) {
            float4 xv = *(const float4*)(xp + k4 * 4);
            float4 bv = *(const float4*)&fbuf[rr * 132 + c0 + k4 * 4];
            float4 ov = {xv.x + bv.x, xv.y + bv.y, xv.z + bv.z, xv.w + bv.w};
            *(float4*)(op + k4 * 4) = ov;
        }
    }
}

extern "C" void kernel_launch(void* const* d_in, const int* in_sizes, int n_in,
                              void* d_out, int out_size, void* d_ws, size_t ws_size,
                              hipStream_t stream) {
    const float* x          = (const float*)d_in[0];
    const float* cond       = (const float*)d_in[2];
    const float* norm_scale = (const float*)d_in[3];
    const float* mod_w      = (const float*)d_in[4];
    const float* mod_b      = (const float*)d_in[5];
    const float* qkv_w      = (const float*)d_in[6];
    const float* attn_scale = (const float*)d_in[7];
    const float* out_w      = (const float*)d_in[8];

    char* ws = (char*)d_ws;
    float* c               = (float*)ws;                               // 6 KB
    unsigned short* xnb    = (unsigned short*)(ws + 8192);             // 67 MB
    unsigned short* qkvwb  = (unsigned short*)(ws + 8192 + 67108864);  // 384 KB
    unsigned short* outwb  = (unsigned short*)(ws + 8192 + 67108864 + 393216);   // 128 KB
    unsigned short* qkv    = (unsigned short*)(ws + 8192 + 67108864 + 524288);   // 201 MB
    float* out             = (float*)d_out;

    hipLaunchKernelGGL(k_mod,  dim3(384),   dim3(256), 0, stream, cond, mod_w, mod_b, c);
    hipLaunchKernelGGL(k_prep, dim3(33024), dim3(256), 0, stream,
                       x, c, norm_scale, qkv_w, out_w, xnb, qkvwb, outwb);
    hipLaunchKernelGGL(k_qkv_mfma, dim3(6144), dim3(256), 0, stream, xnb, qkvwb, attn_scale, qkv);
    hipLaunchKernelGGL(k_attn_out, dim3(2048), dim3(256), 0, stream, qkv, outwb, x, c, out);
}

// Round 10
// 258.195 us; speedup vs baseline: 1.0437x; 1.0437x over previous
//
#include <hip/hip_runtime.h>
#include <hip/hip_bf16.h>
#include <cstdint>

#define DEV __device__ __forceinline__

constexpr int D_   = 256;
constexpr int CF_  = 768;
constexpr int NTOK = 131072;             // 2*256*256
constexpr int SHIFT = 4;
constexpr float EPS_ = 1e-6f;

typedef short bf16x8 __attribute__((ext_vector_type(8)));
typedef float f32x4  __attribute__((ext_vector_type(4)));

DEV float bf2f(unsigned short u) {
    unsigned v = ((unsigned)u) << 16;
    return __builtin_bit_cast(float, v);
}
DEV unsigned short f2bf(float f) {
    unsigned u = __builtin_bit_cast(unsigned, f);
    unsigned r = (u + 0x7fffu + ((u >> 16) & 1u)) >> 16;
    return (unsigned short)r;
}
DEV unsigned cvtpk(float lo, float hi) {      // packed f32->bf16 RNE (no builtin on gfx950)
    unsigned r;
    asm("v_cvt_pk_bf16_f32 %0, %1, %2" : "=v"(r) : "v"(lo), "v"(hi));
    return r;
}
DEV float wave_sum(float v) {
    #pragma unroll
    for (int o = 32; o; o >>= 1) v += __shfl_xor(v, o, 64);
    return v;
}
DEV void gl_lds16(const void* g, void* l) {
    __builtin_amdgcn_global_load_lds(
        (const __attribute__((address_space(1))) void*)g,
        (__attribute__((address_space(3))) void*)l, 16, 0, 0);
}

// ---------------- kernel 1: modulation c = silu(cond) @ mod_w.T + mod_b ----------------
__global__ void k_mod(const float* __restrict__ cond, const float* __restrict__ mod_w,
                      const float* __restrict__ mod_b, float* __restrict__ c) {
    int wv = threadIdx.x >> 6, lane = threadIdx.x & 63;
    int idx = blockIdx.x * 4 + wv;
    int b = idx / (3 * D_), j = idx % (3 * D_);
    float acc = 0.f;
    for (int k = lane; k < CF_; k += 64) {
        float cv = cond[b * CF_ + k];
        float s = cv / (1.f + expf(-cv));
        acc += s * mod_w[(size_t)j * CF_ + k];
    }
    acc = wave_sum(acc);
    if (lane == 0) c[b * (3 * D_) + j] = acc + mod_b[j];
}

// ---------------- kernel 2: merged prep: xn bf16 (RMS+mod) AND weight casts ----------------
__global__ void k_prep(const float* __restrict__ x, const float* __restrict__ c,
                       const float* __restrict__ norm_scale,
                       const float* __restrict__ qkv_w, const float* __restrict__ out_w,
                       unsigned short* __restrict__ xnb,
                       unsigned short* __restrict__ qkvwb, unsigned short* __restrict__ outwb) {
    if (blockIdx.x < 32768) {
        int wv = threadIdx.x >> 6, lane = threadIdx.x & 63;
        int t = blockIdx.x * 4 + wv;
        int b = t >> 16;
        const float* xp = x + (size_t)t * D_ + lane * 4;
        float4 v = *(const float4*)xp;
        float s = v.x * v.x + v.y * v.y + v.z * v.z + v.w * v.w;
        s = wave_sum(s);
        float rinv = rsqrtf(s * (1.f / D_) + EPS_);
        float4 sc = *(const float4*)(c + b * 768 + 256 + lane * 4);
        float4 sh = *(const float4*)(c + b * 768 + lane * 4);
        float4 ns = *(const float4*)(norm_scale + lane * 4);
        float y0 = v.x * rinv * ((1.f + sc.x) * ns.x) + sh.x;
        float y1 = v.y * rinv * ((1.f + sc.y) * ns.y) + sh.y;
        float y2 = v.z * rinv * ((1.f + sc.z) * ns.z) + sh.z;
        float y3 = v.w * rinv * ((1.f + sc.w) * ns.w) + sh.w;
        uint2 p;
        p.x = cvtpk(y0, y1);
        p.y = cvtpk(y2, y3);
        *(uint2*)(xnb + (size_t)t * D_ + lane * 4) = p;
    } else {
        int i = (blockIdx.x - 32768) * 256 + threadIdx.x;
        const float* src; unsigned short* dst; int off;
        if (i < 49152) { src = qkv_w; dst = qkvwb; off = i * 4; }
        else           { src = out_w; dst = outwb; off = (i - 49152) * 4; }
        float4 v = *(const float4*)(src + off);
        uint2 p;
        p.x = cvtpk(v.x, v.y);
        p.y = cvtpk(v.z, v.w);
        *(uint2*)(dst + off) = p;
    }
}

// ---------------- kernel 3: QKV GEMM, 2-phase pipelined, swizzled LDS, wide stores ----
__global__ __launch_bounds__(256) void k_qkv_mfma(const unsigned short* __restrict__ xnb,
                                                  const unsigned short* __restrict__ wb,
                                                  const float* __restrict__ attn_scale,
                                                  unsigned short* __restrict__ qkv) {
    __shared__ unsigned short SM[17408];           // loop: As[2][4096]+Bs[2][4096]; epi: [128][136]
    unsigned short* As = SM;
    unsigned short* Bs = SM + 8192;
    const int t = threadIdx.x, l = t & 63, w = t >> 6;
    const int bid = blockIdx.x;
    const int lid = (bid & 7) * 768 + (bid >> 3);  // 6144 blocks, 8 XCD chunks of 768
    const int m0 = (lid / 6) * 128;
    const int nt = lid % 6;
    const int n0 = nt * 128;
    const int wm = w >> 1, wn = w & 1;
    f32x4 acc[4][4] = {};

    const int srow = w * 32 + (l >> 2);
    const int scol = (((l & 3) ^ ((l >> 3) & 3)) * 8);   // swizzled source slot
    const unsigned short* aA = xnb + (size_t)(m0 + srow) * 256 + scol;
    const unsigned short* aB = wb  + (size_t)(n0 + srow) * 256 + scol;

    auto stage = [&](int buf, int k0) {
        gl_lds16(aA + k0,            &As[buf * 4096 + (w * 2 + 0) * 512]);
        gl_lds16(aA + k0 + 16 * 256, &As[buf * 4096 + (w * 2 + 1) * 512]);
        gl_lds16(aB + k0,            &Bs[buf * 4096 + (w * 2 + 0) * 512]);
        gl_lds16(aB + k0 + 16 * 256, &Bs[buf * 4096 + (w * 2 + 1) * 512]);
    };

    const int q16 = l & 15, g = l >> 4;
    const int rslot = (g ^ ((q16 >> 1) & 3)) * 8;        // swizzled read slot

    stage(0, 0);
    __syncthreads();
    int cur = 0;
    #pragma unroll
    for (int step = 0; step < 8; ++step) {
        if (step < 7) stage(cur ^ 1, (step + 1) * 32);   // prefetch next tile
        bf16x8 af[4], bff[4];
        #pragma unroll
        for (int i = 0; i < 4; i++) {
            af[i]  = *(const bf16x8*)&As[cur * 4096 + (wm * 64 + i * 16 + q16) * 32 + rslot];
            bff[i] = *(const bf16x8*)&Bs[cur * 4096 + (wn * 64 + i * 16 + q16) * 32 + rslot];
        }
        #pragma unroll
        for (int i = 0; i < 4; i++)
            #pragma unroll
            for (int j = 0; j < 4; j++)
                acc[i][j] = __builtin_amdgcn_mfma_f32_16x16x32_bf16(af[i], bff[j], acc[i][j], 0, 0, 0);
        __syncthreads();
        cur ^= 1;
    }

    // ---- epilogue: transform in-register, stage to LDS [128][136], coalesced stores ----
    const int rl0 = wm * 64 + g * 4;
    const int cl0 = wn * 64 + q16;

    if (nt < 4) {
        const int head = (nt * 2 + wn) & 3;
        const float ssc = sqrtf(attn_scale[head]);
        const float freq = expf(1.14472988584940017f + (float)((q16 & 7) * 4 + head) * 0.07195578545544534f);
        #pragma unroll
        for (int i = 0; i < 4; i++) {
            #pragma unroll
            for (int rg = 0; rg < 4; rg++) {
                float ss = acc[i][0][rg] * acc[i][0][rg] + acc[i][1][rg] * acc[i][1][rg]
                         + acc[i][2][rg] * acc[i][2][rg] + acc[i][3][rg] * acc[i][3][rg];
                ss += __shfl_xor(ss, 1, 64);
                ss += __shfl_xor(ss, 2, 64);
                ss += __shfl_xor(ss, 4, 64);
                ss += __shfl_xor(ss, 8, 64);
                const float rinv = ssc * rsqrtf(ss + EPS_);
                const int rl = rl0 + i * 16 + rg;
                const int row = m0 + rl;
                const int oy = (row >> 8) & 255, ox = row & 255;
                const float ph = -1.f + (float)oy * (2.f / 255.f);
                const float pw = -1.f + (float)ox * (2.f / 255.f);
                const float th = ((q16 < 8) ? ph : pw) * freq;
                float sn, cs;
                __sincosf(th, &sn, &cs);
                const float n0v = acc[i][0][rg] * rinv;
                const float n1v = acc[i][1][rg] * rinv;
                const float n2v = acc[i][2][rg] * rinv;
                const float n3v = acc[i][3][rg] * rinv;
                SM[rl * 136 + cl0]      = f2bf(n0v * cs - n1v * sn);
                SM[rl * 136 + cl0 + 16] = f2bf(n1v * cs + n0v * sn);
                SM[rl * 136 + cl0 + 32] = f2bf(n2v);
                SM[rl * 136 + cl0 + 48] = f2bf(n3v);
            }
        }
    } else {
        #pragma unroll
        for (int i = 0; i < 4; i++)
            #pragma unroll
            for (int rg = 0; rg < 4; rg++) {
                const int rl = rl0 + i * 16 + rg;
                #pragma unroll
                for (int j = 0; j < 4; j++)
                    SM[rl * 136 + cl0 + j * 16] = f2bf(acc[i][j][rg]);
            }
    }
    __syncthreads();

    {
        const int cr = (t & 15) * 8, rr = t >> 4;
        #pragma unroll
        for (int it = 0; it < 8; it++) {
            const int rl = rr + it * 16;
            uint4 vv = *(const uint4*)&SM[rl * 136 + cr];
            *(uint4*)(qkv + (size_t)(m0 + rl) * 768 + n0 + cr) = vv;
        }
    }
}

// ---------------- kernel 4: fused window attention + out-projection + gated residual ----
// Block = 1 window, 4 waves = 4 heads (independent phases -> T5 setprio pays).
// S^T = mfma(K,Q); softmax in-register; P in-register via cvt_pk + shfl; V^T in LDS;
// Mem reused as ostage [64][264] bf16 for the out-GEMM; round-8 scalar epilogue.
__global__ __launch_bounds__(256) void k_attn_out(const unsigned short* __restrict__ qkv,
                                                  const unsigned short* __restrict__ outwb,
                                                  const float* __restrict__ x,
                                                  const float* __restrict__ c,
                                                  float* __restrict__ out) {
    __shared__ unsigned short Mem[4 * 64 * 72];    // per-wave V^T; reused as ostage[64][264]
    __shared__ float Ls[4][64];
    const int w = threadIdx.x >> 6, l = threadIdx.x & 63;
    const int bid = blockIdx.x;
    const int lid = (bid & 7) * 256 + (bid >> 3);  // XCD-contiguous windows
    const int wx = lid & 31, wy = (lid >> 5) & 31, b = lid >> 10;
    const int head = w;
    const int g = l >> 4, q16 = l & 15;
    unsigned short* Vt = &Mem[w * 4608];

    auto tokof = [&](int p) -> size_t {
        int oy = (wy * 8 + (p >> 3) - SHIFT) & 255;
        int ox = (wx * 8 + (p & 7) - SHIFT) & 255;
        return (size_t)b * 65536 + (size_t)oy * 256 + ox;
    };

    // ---- stage V^T (this wave's head): Vt[d][key] ----
    {
        const unsigned short* vp = qkv + tokof(l) * 768 + 512 + head * 64;
        uint4 vr[8];
        #pragma unroll
        for (int i = 0; i < 8; i++) vr[i] = *(const uint4*)(vp + i * 8);
        #pragma unroll
        for (int i = 0; i < 8; i++) {
            unsigned wd[4] = {vr[i].x, vr[i].y, vr[i].z, vr[i].w};
            #pragma unroll
            for (int cc = 0; cc < 4; cc++) {
                Vt[(i * 8 + cc * 2 + 0) * 72 + l] = (unsigned short)(wd[cc] & 0xffff);
                Vt[(i * 8 + cc * 2 + 1) * 72 + l] = (unsigned short)(wd[cc] >> 16);
            }
        }
    }

    // ---- K (A) and Q (B) fragments direct from global ----
    bf16x8 af[4][2], bq[4][2];
    #pragma unroll
    for (int i = 0; i < 4; i++) {
        size_t tk = tokof(i * 16 + q16);
        const unsigned short* kp = qkv + tk * 768 + 256 + head * 64 + g * 8;
        af[i][0] = *(const bf16x8*)(kp);
        af[i][1] = *(const bf16x8*)(kp + 32);
        const unsigned short* qp = qkv + tk * 768 + head * 64 + g * 8;
        bq[i][0] = *(const bf16x8*)(qp);
        bq[i][1] = *(const bf16x8*)(qp + 32);
    }

    // ---- S^T = K @ Q^T ----
    f32x4 st[4][4] = {};
    __builtin_amdgcn_s_setprio(1);
    #pragma unroll
    for (int ks = 0; ks < 2; ks++)
        #pragma unroll
        for (int i = 0; i < 4; i++)
            #pragma unroll
            for (int j = 0; j < 4; j++)
                st[i][j] = __builtin_amdgcn_mfma_f32_16x16x32_bf16(af[i][ks], bq[j][ks], st[i][j], 0, 0, 0);
    __builtin_amdgcn_s_setprio(0);

    // ---- boundary-window mask ----
    const bool topw = (wy == 0), leftw = (wx == 0);
    if (topw || leftw) {
        #pragma unroll
        for (int j = 0; j < 4; j++) {
            int query = 16 * j + q16;
            bool qa = ((query >> 3) < 4), qlf = ((query & 7) < 4);
            #pragma unroll
            for (int i = 0; i < 4; i++)
                #pragma unroll
                for (int r = 0; r < 4; r++) {
                    int key = 16 * i + 4 * g + r;
                    bool ok = (!leftw || (qlf == ((key & 7) < 4))) &&
                              (!topw || (qa == ((key >> 3) < 4)));
                    if (!ok) st[i][j][r] = -1e9f;
                }
        }
    }

    // ---- softmax over keys ----
    #pragma unroll
    for (int j = 0; j < 4; j++) {
        float m = -1e30f;
        #pragma unroll
        for (int i = 0; i < 4; i++)
            #pragma unroll
            for (int r = 0; r < 4; r++) m = fmaxf(m, st[i][j][r]);
        m = fmaxf(m, __shfl_xor(m, 16, 64));
        m = fmaxf(m, __shfl_xor(m, 32, 64));
        float s = 0.f;
        #pragma unroll
        for (int i = 0; i < 4; i++)
            #pragma unroll
            for (int r = 0; r < 4; r++) {
                float p = __expf(st[i][j][r] - m);
                st[i][j][r] = p;
                s += p;
            }
        s += __shfl_xor(s, 16, 64);
        s += __shfl_xor(s, 32, 64);
        if (g == 0) Ls[w][16 * j + q16] = s;
    }
    __syncthreads();    // Vt fully staged

    // ---- PV with in-register P transpose ----
    bf16x8 vb[4][2];
    #pragma unroll
    for (int j = 0; j < 4; j++) {
        vb[j][0] = *(const bf16x8*)&Vt[(16 * j + q16) * 72 + g * 8];
        vb[j][1] = *(const bf16x8*)&Vt[(16 * j + q16) * 72 + 32 + g * 8];
    }
    const int ghi = g >> 1;
    const int srcl0 = ((2 * (g & 1)) & 3) * 16 + q16;
    const int srcl1 = ((2 * (g & 1) + 1) & 3) * 16 + q16;
    f32x4 o[4][4] = {};
    #pragma unroll
    for (int qb = 0; qb < 4; qb++) {
        unsigned pk[8];
        #pragma unroll
        for (int ih = 0; ih < 4; ih++) {
            pk[2 * ih]     = cvtpk(st[ih][qb][0], st[ih][qb][1]);
            pk[2 * ih + 1] = cvtpk(st[ih][qb][2], st[ih][qb][3]);
        }
        unsigned pw[8];
        #pragma unroll
        for (int ks = 0; ks < 2; ks++) {
            #pragma unroll
            for (int wd = 0; wd < 4; wd++) {
                const int srcl = (wd < 2) ? srcl0 : srcl1;
                unsigned va  = (unsigned)__shfl((int)pk[4 * ks + (wd & 1)], srcl, 64);
                unsigned vbb = (unsigned)__shfl((int)pk[4 * ks + 2 + (wd & 1)], srcl, 64);
                pw[ks * 4 + wd] = ghi ? vbb : va;
            }
        }
        uint4 paw0 = {pw[0], pw[1], pw[2], pw[3]};
        uint4 paw1 = {pw[4], pw[5], pw[6], pw[7]};
        bf16x8 paA = __builtin_bit_cast(bf16x8, paw0);
        bf16x8 paB = __builtin_bit_cast(bf16x8, paw1);
        __builtin_amdgcn_s_setprio(1);
        #pragma unroll
        for (int j = 0; j < 4; j++) {
            o[qb][j] = __builtin_amdgcn_mfma_f32_16x16x32_bf16(paA, vb[j][0], o[qb][j], 0, 0, 0);
            o[qb][j] = __builtin_amdgcn_mfma_f32_16x16x32_bf16(paB, vb[j][1], o[qb][j], 0, 0, 0);
        }
        __builtin_amdgcn_s_setprio(0);
    }

    // ---- scale by 1/l, stage O bf16 into LDS [64][264] ----
    __syncthreads();
    unsigned short* ost = Mem;
    #pragma unroll
    for (int i = 0; i < 4; i++) {
        float4 lv = *(const float4*)&Ls[w][16 * i + 4 * g];
        float lvr[4] = {lv.x, lv.y, lv.z, lv.w};
        #pragma unroll
        for (int r = 0; r < 4; r++) {
            const float invl = 1.f / lvr[r];
            const int row = 16 * i + 4 * g + r;
            #pragma unroll
            for (int j = 0; j < 4; j++)
                ost[row * 264 + head * 64 + 16 * j + q16] = f2bf(o[i][j][r] * invl);
        }
    }
    __syncthreads();

    // ---- out projection: wave w computes cols [64w, 64w+64) ----
    f32x4 acc2[4][4] = {};
    #pragma unroll
    for (int ks = 0; ks < 8; ks++) {
        bf16x8 a2[4], b2[4];
        #pragma unroll
        for (int i = 0; i < 4; i++)
            a2[i] = *(const bf16x8*)&ost[(16 * i + q16) * 264 + ks * 32 + g * 8];
        #pragma unroll
        for (int j = 0; j < 4; j++)
            b2[j] = *(const bf16x8*)&outwb[(size_t)(w * 64 + 16 * j + q16) * 256 + ks * 32 + g * 8];
        __builtin_amdgcn_s_setprio(1);
        #pragma unroll
        for (int i = 0; i < 4; i++)
            #pragma unroll
            for (int j = 0; j < 4; j++)
                acc2[i][j] = __builtin_amdgcn_mfma_f32_16x16x32_bf16(a2[i], b2[j], acc2[i][j], 0, 0, 0);
        __builtin_amdgcn_s_setprio(0);
    }

    // ---- gated residual + f32 store (round-8 proven form) ----
    float gates[4];
    #pragma unroll
    for (int j = 0; j < 4; j++) gates[j] = c[b * 768 + 512 + w * 64 + 16 * j + q16];
    #pragma unroll
    for (int i = 0; i < 4; i++) {
        #pragma unroll
        for (int r = 0; r < 4; r++) {
            const int row = 16 * i + 4 * g + r;
            const size_t tok = tokof(row);
            float* op = out + tok * 256 + w * 64 + q16;
            const float* xp = x + tok * 256 + w * 64 + q16;
            #pragma unroll
            for (int j = 0; j < 4; j++)
                op[16 * j] = xp[16 * j] + gates[j] * acc2[i][j][r];
        }
    }
}

extern "C" void kernel_launch(void* const* d_in, const int* in_sizes, int n_in,
                              void* d_out, int out_size, void* d_ws, size_t ws_size,
                              hipStream_t stream) {
    const float* x          = (const float*)d_in[0];
    const float* cond       = (const float*)d_in[2];
    const float* norm_scale = (const float*)d_in[3];
    const float* mod_w      = (const float*)d_in[4];
    const float* mod_b      = (const float*)d_in[5];
    const float* qkv_w      = (const float*)d_in[6];
    const float* attn_scale = (const float*)d_in[7];
    const float* out_w      = (const float*)d_in[8];

    char* ws = (char*)d_ws;
    float* c               = (float*)ws;                               // 6 KB
    unsigned short* xnb    = (unsigned short*)(ws + 8192);             // 67 MB
    unsigned short* qkvwb  = (unsigned short*)(ws + 8192 + 67108864);  // 384 KB
    unsigned short* outwb  = (unsigned short*)(ws + 8192 + 67108864 + 393216);   // 128 KB
    unsigned short* qkv    = (unsigned short*)(ws + 8192 + 67108864 + 524288);   // 201 MB
    float* out             = (float*)d_out;

    hipLaunchKernelGGL(k_mod,  dim3(384),   dim3(256), 0, stream, cond, mod_w, mod_b, c);
    hipLaunchKernelGGL(k_prep, dim3(33024), dim3(256), 0, stream,
                       x, c, norm_scale, qkv_w, out_w, xnb, qkvwb, outwb);
    hipLaunchKernelGGL(k_qkv_mfma, dim3(6144), dim3(256), 0, stream, xnb, qkvwb, attn_scale, qkv);
    hipLaunchKernelGGL(k_attn_out, dim3(2048), dim3(256), 0, stream, qkv, outwb, x, c, out);
}